// Round 14
// baseline (108.286 us; speedup 1.0000x reference)
//
#include <hip/hip_runtime.h>
#include <hip/hip_bf16.h>
#include <math.h>

#define DD 768
#define BB 32
#define PP 512
#define TT 512
#define CC 97
#define THRESH 0.8f
#define BK 32

typedef __attribute__((ext_vector_type(8))) short short8;
typedef __attribute__((ext_vector_type(4))) float f32x4;
typedef float4 f4u __attribute__((aligned(4)));

__device__ __forceinline__ short bfc(float x) {
    __hip_bfloat16 h = __float2bfloat16(x);
    return *(short*)&h;
}

// ---------------- fused match: raw fp32 -> bf16 staged dual-GEMM -------------
// Cosine trick (R10-verified): stage RAW values (fp32->bf16 in regs), MFMA
// raw dots, per-row sum-of-squares from the same fp32 staging regs, epilogue
// scales by rsqrt(nA)*rsqrt(nB).
// R14: occupancy via BLOCK GRANULARITY, not register dieting (R13 failed:
// allocator stays at 144 unified). At 144 regs HW gives 3 waves/SIMD = 12
// waves/CU; a 4-WAVE block -> 3 blocks/CU (8-wave gets only 1). Tile
// 128p x 64t, waves 0-1 = H (p-halves), 2-3 = T; LDS 2x24KB+norms = 49.7KB
// (3 x 49.7 = 149KB < 160). Grid 1024 = 4pblk x 8tblk x 32b, XCD-swizzled.
// 6 staging pieces/thread, ONE reused 4xfloat4 set, 3 sub-rounds interleaved
// with 4 MFMA quartets. Independent blocks overlap each other's stalls.
__global__ __launch_bounds__(256, 2) void match_kernel(
        const float* __restrict__ pairs, const float* __restrict__ trip,
        float* __restrict__ cand_v, int* __restrict__ cand_t) {
    __shared__ __align__(16) char smem[49152];    // 2 x 24KB (Ah8|At8|Bh4|Bt4)
    __shared__ float norms[384];                  // [Ah128|At128|Bh64|Bt64]

    // XCD swizzle (1024 blocks, %8==0 -> bijective); 32 consecutive = 1 batch
    int bid = blockIdx.x;
    int swz = (bid & 7) * 128 + (bid >> 3);
    int b = swz >> 5, sub = swz & 31;
    int pblk = sub >> 3, tblk = sub & 7;          // 4 p-blocks x 8 t-blocks

    int tid = threadIdx.x;                        // 256 threads = 4 waves
    int w = tid >> 6, l = tid & 63;
    int l15 = l & 15, lg = l >> 4;
    int ln = tid & 3;

    const float* pairs_b = pairs + ((size_t)b * PP + pblk * 128) * (2 * DD);
    const float* trip_b  = trip  + ((size_t)b * TT + tblk * 64) * (2 * DD + 1);

    // staging: 6 pieces/thread, 16B each; seg s = tid + 256r, row = s>>2,
    // lane ln = s&3; source chunk = ln ^ ((row>>1)&3) (swizzle src side).
    // pieces: 0 = Ah rows 0-63, 1 = Ah 64-127 (+64*1536), 2 = At 0-63 (+768),
    // 3 = At 64-127, 4 = Bh rows 0-63 (trip head), 5 = Bt 0-63 (+769).
    // All pieces share row srow = tid>>2 and the same chunk xor (row%64 equal).
    int srow = tid >> 2;
    int xch_c = ln ^ ((srow >> 1) & 3);
    const float* sp0 = pairs_b + (size_t)srow * 1536 + xch_c * 8;
    const float* sp4 = trip_b + (size_t)srow * 1537 + xch_c * 8;
    int dst = tid * 16;                           // piece r dest = dst + r*4096

    float4 xa0, xb0, xa1, xb1;                    // ONE reused staging set
    float sq0 = 0.f, sq1 = 0.f, sq2 = 0.f, sq3 = 0.f, sq4 = 0.f, sq5 = 0.f;

#define LD01(ko)                                                              \
    do {                                                                      \
        xa0 = *(const f4u*)(sp0 + (ko));          xb0 = *(const f4u*)(sp0 + (ko) + 4); \
        xa1 = *(const f4u*)(sp0 + (ko) + 98304);  xb1 = *(const f4u*)(sp0 + (ko) + 98308); \
    } while (0)
#define LD23(ko)                                                              \
    do {                                                                      \
        xa0 = *(const f4u*)(sp0 + (ko) + 768);    xb0 = *(const f4u*)(sp0 + (ko) + 772); \
        xa1 = *(const f4u*)(sp0 + (ko) + 99072);  xb1 = *(const f4u*)(sp0 + (ko) + 99076); \
    } while (0)
#define LD45(ko)                                                              \
    do {                                                                      \
        xa0 = *(const f4u*)(sp4 + (ko));          xb0 = *(const f4u*)(sp4 + (ko) + 4); \
        xa1 = *(const f4u*)(sp4 + (ko) + 769);    xb1 = *(const f4u*)(sp4 + (ko) + 773); \
    } while (0)
#define WRQ(sqv, nb, off, A, Bv)                                              \
    do {                                                                      \
        sqv += A.x*A.x + A.y*A.y + A.z*A.z + A.w*A.w                          \
             + Bv.x*Bv.x + Bv.y*Bv.y + Bv.z*Bv.z + Bv.w*Bv.w;                 \
        short8 pk;                                                            \
        pk[0]=bfc(A.x); pk[1]=bfc(A.y); pk[2]=bfc(A.z); pk[3]=bfc(A.w);       \
        pk[4]=bfc(Bv.x); pk[5]=bfc(Bv.y); pk[6]=bfc(Bv.z); pk[7]=bfc(Bv.w);   \
        *(short8*)(smem + (nb) + dst + (off)) = pk;                           \
    } while (0)
#define WR01(nb) do { WRQ(sq0, nb, 0, xa0, xb0); WRQ(sq1, nb, 4096, xa1, xb1); } while (0)
#define WR23(nb) do { WRQ(sq2, nb, 8192, xa0, xb0); WRQ(sq3, nb, 12288, xa1, xb1); } while (0)
#define WR45(nb) do { WRQ(sq4, nb, 16384, xa0, xb0); WRQ(sq5, nb, 20480, xa1, xb1); } while (0)

    // read addressing: row pitch 64B; phys slot = lg ^ ((l15>>1)&3)
    int isH = (w >> 1) == 0;
    int ph = w & 1;                               // p-half 0/1
    int Aoff = isH ? 0 : 8192;
    int Boff = isH ? 16384 : 20480;
    int slot = (lg ^ ((l15 >> 1) & 3)) * 16;
    int Abase = Aoff + (ph * 64 + l15) * 64 + slot;   // +i*1024
    int Bbase = Boff + l15 * 64 + slot;               // +j*1024

    f32x4 c00 = {0.f,0.f,0.f,0.f}, c01 = c00, c02 = c00, c03 = c00;
    f32x4 c10 = c00, c11 = c00, c12 = c00, c13 = c00;
    f32x4 c20 = c00, c21 = c00, c22 = c00, c23 = c00;
    f32x4 c30 = c00, c31 = c00, c32 = c00, c33 = c00;

#define MM(i, j, fa, fb) c##i##j = __builtin_amdgcn_mfma_f32_16x16x32_bf16(fa, fb, c##i##j, 0, 0, 0)
// quartets: live frag set = fa0,fa1,g0,g1 (16 regs); A-pair re-read in QC.
#define QA(cb)                                                                \
    do { const char* bp = smem + (cb);                                        \
        fa0 = *(const short8*)(bp + Abase + 0);                               \
        fa1 = *(const short8*)(bp + Abase + 1024);                            \
        g0  = *(const short8*)(bp + Bbase + 0);                               \
        g1  = *(const short8*)(bp + Bbase + 1024);                            \
        __builtin_amdgcn_s_setprio(1);                                        \
        MM(0,0,fa0,g0); MM(1,0,fa1,g0); MM(0,1,fa0,g1); MM(1,1,fa1,g1);       \
        __builtin_amdgcn_s_setprio(0);                                        \
    } while (0)
#define QB(cb)                                                                \
    do { const char* bp = smem + (cb);                                        \
        g0 = *(const short8*)(bp + Bbase + 2048);                             \
        g1 = *(const short8*)(bp + Bbase + 3072);                             \
        __builtin_amdgcn_s_setprio(1);                                        \
        MM(0,2,fa0,g0); MM(1,2,fa1,g0); MM(0,3,fa0,g1); MM(1,3,fa1,g1);       \
        __builtin_amdgcn_s_setprio(0);                                        \
    } while (0)
#define QC(cb)                                                                \
    do { const char* bp = smem + (cb);                                        \
        fa0 = *(const short8*)(bp + Abase + 2048);                            \
        fa1 = *(const short8*)(bp + Abase + 3072);                            \
        g0  = *(const short8*)(bp + Bbase + 0);                               \
        g1  = *(const short8*)(bp + Bbase + 1024);                            \
        __builtin_amdgcn_s_setprio(1);                                        \
        MM(2,0,fa0,g0); MM(3,0,fa1,g0); MM(2,1,fa0,g1); MM(3,1,fa1,g1);       \
        __builtin_amdgcn_s_setprio(0);                                        \
    } while (0)
#define QD(cb)                                                                \
    do { const char* bp = smem + (cb);                                        \
        g0 = *(const short8*)(bp + Bbase + 2048);                             \
        g1 = *(const short8*)(bp + Bbase + 3072);                             \
        __builtin_amdgcn_s_setprio(1);                                        \
        MM(2,2,fa0,g0); MM(3,2,fa1,g0); MM(2,3,fa0,g1); MM(3,3,fa1,g1);       \
        __builtin_amdgcn_s_setprio(0);                                        \
    } while (0)

    // prologue: tile 0 -> buf0 (three sub-rounds, serial — once only)
    LD01(0); WR01(0);
    LD23(0); WR23(0);
    LD45(0); WR45(0);
    __syncthreads();

#pragma unroll 2
    for (int t = 0; t < 24; ++t) {
        int cb = (t & 1) * 24576;
        int nb = cb ^ 24576;
        size_t ko = (size_t)(t + 1) * BK;
        short8 fa0, fa1, g0, g1;
        if (t < 23) LD01(ko);                 // loads fly under QA
        QA(cb);
        if (t < 23) { WR01(nb); LD23(ko); }   // loads fly under QB
        QB(cb);
        if (t < 23) { WR23(nb); LD45(ko); }   // loads fly under QC
        QC(cb);
        if (t < 23) WR45(nb);
        QD(cb);
        __syncthreads();
    }
#undef QA
#undef QB
#undef QC
#undef QD
#undef MM
#undef WR01
#undef WR23
#undef WR45
#undef WRQ
#undef LD01
#undef LD23
#undef LD45

    // finalize norms: quad-reduce (lanes ln=0..3 share a row)
    sq0 += __shfl_xor(sq0, 1); sq0 += __shfl_xor(sq0, 2);
    sq1 += __shfl_xor(sq1, 1); sq1 += __shfl_xor(sq1, 2);
    sq2 += __shfl_xor(sq2, 1); sq2 += __shfl_xor(sq2, 2);
    sq3 += __shfl_xor(sq3, 1); sq3 += __shfl_xor(sq3, 2);
    sq4 += __shfl_xor(sq4, 1); sq4 += __shfl_xor(sq4, 2);
    sq5 += __shfl_xor(sq5, 1); sq5 += __shfl_xor(sq5, 2);
    if (ln == 0) {
        norms[srow] = sq0;                    // Ah rows 0-63
        norms[64 + srow] = sq1;               // Ah rows 64-127
        norms[128 + srow] = sq2;              // At rows 0-63
        norms[192 + srow] = sq3;              // At rows 64-127
        norms[256 + srow] = sq4;              // Bh rows 0-63
        norms[320 + srow] = sq5;              // Bt rows 0-63
    }
    __syncthreads();

    // scale raw dots -> cosines: c[i][j][r] *= rsqrt(nA[p]) * rsqrt(nB[t])
    {
        const float* nA = norms + (isH ? 0 : 128);
        const float* nB = norms + (isH ? 256 : 320);
        float ivB0 = rsqrtf(nB[0 * 16 + l15]);
        float ivB1 = rsqrtf(nB[1 * 16 + l15]);
        float ivB2 = rsqrtf(nB[2 * 16 + l15]);
        float ivB3 = rsqrtf(nB[3 * 16 + l15]);
#define SCJ(ii, jj) { c##ii##jj[0] *= s0 * ivB##jj; c##ii##jj[1] *= s1 * ivB##jj; \
                      c##ii##jj[2] *= s2 * ivB##jj; c##ii##jj[3] *= s3 * ivB##jj; }
#define SCA(ii) { float s0 = rsqrtf(nA[ph * 64 + ii * 16 + lg * 4 + 0]);      \
                  float s1 = rsqrtf(nA[ph * 64 + ii * 16 + lg * 4 + 1]);      \
                  float s2 = rsqrtf(nA[ph * 64 + ii * 16 + lg * 4 + 2]);      \
                  float s3 = rsqrtf(nA[ph * 64 + ii * 16 + lg * 4 + 3]);      \
                  SCJ(ii,0) SCJ(ii,1) SCJ(ii,2) SCJ(ii,3) }
        SCA(0) SCA(1) SCA(2) SCA(3)
#undef SCA
#undef SCJ
    }
    __syncthreads();

    // epilogue: H-wave (0,1) + T-wave (2,3) pair by p-half via swizzled LDS.
    float* bwv = (float*)(smem + 16384);          // [128]
    int*   bwt = (int*)(smem + 17408);            // [128]
    char* xrow = smem + (ph * 64 + l) * 64;       // 8KB exchange region
    int qsw = (l >> 1) & 3;

#define XW(q, v) *(f32x4*)(xrow + (((q) ^ qsw) * 16)) = (v)
#define XR(q)    *(const f32x4*)(xrow + (((q) ^ qsw) * 16))

#define ASTEP(ii, jj, rr, TQ)                                                 \
        { float h = c##ii##jj[rr]; float tv = (TQ)[rr];                       \
          bool ok = (h > THRESH) && (tv > THRESH);                            \
          float sc = ok ? 0.5f * (h + tv) : -INFINITY;                        \
          if (sc > bv) { bv = sc; bt = jj * 16 + l15; } }

#define AMX(ii, rr)                                                           \
    {   float bv = -INFINITY; int bt = 0x7fffffff;                            \
        ASTEP(ii, 0, rr, t0) ASTEP(ii, 1, rr, t1)                             \
        ASTEP(ii, 2, rr, t2) ASTEP(ii, 3, rr, t3)                             \
        for (int m = 1; m < 16; m <<= 1) {                                    \
            float v2 = __shfl_xor(bv, m); int q2 = __shfl_xor(bt, m);         \
            if (v2 > bv || (v2 == bv && q2 < bt)) { bv = v2; bt = q2; }       \
        }                                                                     \
        if (l15 == 0) { int p = ph * 64 + ii * 16 + lg * 4 + rr;              \
            bwv[p] = bv; bwt[p] = bt; }                                       \
    }

#define EPI(ii)                                                               \
    if (!isH) { XW(0, c##ii##0); XW(1, c##ii##1);                             \
                XW(2, c##ii##2); XW(3, c##ii##3); }                           \
    __syncthreads();                                                          \
    if (isH) {                                                                \
        f32x4 t0 = XR(0), t1 = XR(1), t2 = XR(2), t3 = XR(3);                 \
        AMX(ii, 0) AMX(ii, 1) AMX(ii, 2) AMX(ii, 3)                           \
    }                                                                         \
    __syncthreads();

    EPI(0)
    EPI(1)
    EPI(2)
    EPI(3)
#undef EPI
#undef AMX
#undef ASTEP
#undef XW
#undef XR

    if (tid < 128) {
        float v = bwv[tid]; int t1 = bwt[tid];
        int grow = b * PP + pblk * 128 + tid;
        cand_v[(size_t)grow * 8 + tblk] = v;
        cand_t[(size_t)grow * 8 + tblk] = (v > -INFINITY) ? (tblk * 64 + t1) : 0x7fffffff;
    }
}

// ---------------- stage 3: fused merge + per-row NLL -------------------------
// block = 256 = 4 waves, one row per wave. Lanes 0-7 merge the 8 t-block
// candidates; rel id read directly from trip column D; wave log-softmax C=97.
__global__ void nll_kernel(const float* __restrict__ preds,
                           const float* __restrict__ cand_v,
                           const int* __restrict__ cand_t,
                           const float* __restrict__ trip,
                           float* __restrict__ partials) {
    int w = threadIdx.x >> 6, l = threadIdx.x & 63;
    int row = blockIdx.x * 4 + w;
    const float* x = preds + (size_t)row * CC;

    float v = (l < 8) ? cand_v[(size_t)row * 8 + l] : -INFINITY;
    int  tt = (l < 8) ? cand_t[(size_t)row * 8 + l] : 0x7fffffff;
#pragma unroll
    for (int m = 1; m < 8; m <<= 1) {
        float v2 = __shfl_xor(v, m); int t2 = __shfl_xor(tt, m);
        if (v2 > v || (v2 == v && t2 < tt)) { v = v2; tt = t2; }
    }
    int bb = row >> 9;
    int tg = 0;
    if (l == 0 && v > -INFINITY)
        tg = (int)trip[((size_t)bb * TT + tt) * (2 * DD + 1) + DD];
    tg = __shfl(tg, 0);

    float a = x[l];
    float b2 = (l + 64 < CC) ? x[l + 64] : -INFINITY;
    float mx = fmaxf(a, b2);
    for (int m = 32; m; m >>= 1) mx = fmaxf(mx, __shfl_xor(mx, m));
    float e = __expf(a - mx) + ((l + 64 < CC) ? __expf(b2 - mx) : 0.0f);
    for (int m = 32; m; m >>= 1) e += __shfl_xor(e, m);

    __shared__ float part[4];
    if (l == 0) part[w] = mx + logf(e) - x[tg];
    __syncthreads();
    if (threadIdx.x == 0)
        partials[blockIdx.x] = part[0] + part[1] + part[2] + part[3];
}

// ---------------- stage 4: final mean ----------------------------------------
__global__ void final_reduce_kernel(const float* __restrict__ partials, int n,
                                    float* __restrict__ out) {
    float s = 0.f;
    for (int i = threadIdx.x; i < n; i += 256) s += partials[i];
    for (int m = 32; m; m >>= 1) s += __shfl_xor(s, m);
    __shared__ float ps[4];
    if ((threadIdx.x & 63) == 0) ps[threadIdx.x >> 6] = s;
    __syncthreads();
    if (threadIdx.x == 0)
        out[0] = (ps[0] + ps[1] + ps[2] + ps[3]) / (float)(BB * PP);
}

extern "C" void kernel_launch(void* const* d_in, const int* in_sizes, int n_in,
                              void* d_out, int out_size, void* d_ws, size_t ws_size,
                              hipStream_t stream) {
    const float* pairs = (const float*)d_in[0];  // [B,P,1536]
    const float* preds = (const float*)d_in[1];  // [B,P,97]
    const float* trip  = (const float*)d_in[2];  // [B,T,1537]
    float* out = (float*)d_out;

    char* p = (char*)d_ws;
    float* cand_v = (float*)p;       p += (size_t)BB * PP * 8 * sizeof(float);  // 512KB
    int* cand_t = (int*)p;           p += (size_t)BB * PP * 8 * sizeof(int);    // 512KB
    float* partials = (float*)p;                                                // 16KB

    match_kernel<<<BB * 32, 256, 0, stream>>>(pairs, trip, cand_v, cand_t);
    nll_kernel<<<BB * PP / 4, 256, 0, stream>>>(preds, cand_v, cand_t, trip, partials);
    final_reduce_kernel<<<1, 256, 0, stream>>>(partials, BB * PP / 4, out);
}

// Round 15
// 91.483 us; speedup vs baseline: 1.1837x; 1.1837x over previous
//
#include <hip/hip_runtime.h>
#include <hip/hip_bf16.h>
#include <math.h>

#define DD 768
#define BB 32
#define PP 512
#define TT 512
#define CC 97
#define THRESH 0.8f
#define BK 32

typedef __attribute__((ext_vector_type(8))) short short8;
typedef __attribute__((ext_vector_type(4))) float f32x4;
typedef float4 f4u __attribute__((aligned(4)));

__device__ __forceinline__ short bfc(float x) {
    __hip_bfloat16 h = __float2bfloat16(x);
    return *(short*)&h;
}

// ---------------- fused match: raw fp32 -> bf16 staged dual-GEMM -------------
// Cosine trick (R10-verified): stage RAW values (fp32->bf16 in regs), MFMA
// raw dots, per-row sum-of-squares from the same fp32 staging regs, epilogue
// scales by rsqrt(nA)*rsqrt(nB).
// R15: 3-tiles-deep register pipeline. Two full staging sets (E = even
// tiles, O = odd, 8 float4 each); iter t: COMPUTE(buf t%2) -> WRSET(tile t+1
// from its set -> other buf) -> LDSET(tile t+3 -> same set) -> barrier.
// A tile's loads rest TWO full iterations before the ds_write -> zero vmcnt
// stall (the invariant 4-6k cyc/step across R10-R14 was exposed load
// latency; 1-deep coverage = one COMPUTE ~300cyc < L3/HBM 500-900cyc).
// unroll 2 makes set choice static (rule #20). ~185 unified regs <= 256 cap.
__global__ __launch_bounds__(512, 2) void match_kernel(
        const float* __restrict__ pairs, const float* __restrict__ trip,
        float* __restrict__ cand_v, int* __restrict__ cand_t) {
    __shared__ __align__(16) char smem[65536];    // 2 x 32KB (Ah8|At8|Bh8|Bt8)
    __shared__ float norms[512];                  // [Ah128|At128|Bh128|Bt128]

    // XCD swizzle (512 blocks, %8==0 -> bijective); 16 consecutive = 1 batch
    int bid = blockIdx.x;
    int swz = (bid & 7) * 64 + (bid >> 3);
    int b = swz >> 4, sub = swz & 15;
    int pblk = sub >> 2, tblk = sub & 3;          // 4 p-blocks x 4 t-blocks

    int tid = threadIdx.x;
    int w = tid >> 6, l = tid & 63;
    int l15 = l & 15, lg = l >> 4;
    int ln = tid & 3;

    const float* pairs_b = pairs + ((size_t)b * PP + pblk * 128) * (2 * DD);
    const float* trip_b  = trip  + ((size_t)b * TT + tblk * 128) * (2 * DD + 1);

    // staging: 4 pieces/thread, row r = tid>>2 (0..127), 16B lane ln.
    // source chunk = ln ^ ((r>>1)&3) (swizzle src side; read applies same).
    // pieces 0,1 = pairs row (Ah, At at +768); 2,3 = trip row (Bh, Bt at +769).
    int srow = tid >> 2;
    int xch_c = ln ^ ((srow >> 1) & 3);
    const float* sp0 = pairs_b + (size_t)srow * 1536 + xch_c * 8;
    const float* sp2 = trip_b + (size_t)srow * 1537 + xch_c * 8;
    int dst = tid * 16;

    // two full staging sets (8 float4 each): E = even tiles, O = odd tiles
    float4 E0, E1, E2, E3, E4, E5, E6, E7;
    float4 O0, O1, O2, O3, O4, O5, O6, O7;
    float sq0 = 0.f, sq1 = 0.f, sq2 = 0.f, sq3 = 0.f;

#define LDSET(P, ko)                                                          \
    do {                                                                      \
        P##0 = *(const f4u*)(sp0 + (ko));        P##1 = *(const f4u*)(sp0 + (ko) + 4);   \
        P##2 = *(const f4u*)(sp0 + (ko) + 768);  P##3 = *(const f4u*)(sp0 + (ko) + 772); \
        P##4 = *(const f4u*)(sp2 + (ko));        P##5 = *(const f4u*)(sp2 + (ko) + 4);   \
        P##6 = *(const f4u*)(sp2 + (ko) + 769);  P##7 = *(const f4u*)(sp2 + (ko) + 773); \
    } while (0)
#define WRQ(sqv, nb, off, A, Bv)                                              \
    do {                                                                      \
        sqv += A.x*A.x + A.y*A.y + A.z*A.z + A.w*A.w                          \
             + Bv.x*Bv.x + Bv.y*Bv.y + Bv.z*Bv.z + Bv.w*Bv.w;                 \
        short8 pk;                                                            \
        pk[0]=bfc(A.x); pk[1]=bfc(A.y); pk[2]=bfc(A.z); pk[3]=bfc(A.w);       \
        pk[4]=bfc(Bv.x); pk[5]=bfc(Bv.y); pk[6]=bfc(Bv.z); pk[7]=bfc(Bv.w);   \
        *(short8*)(smem + (nb) + dst + (off)) = pk;                           \
    } while (0)
#define WRSET(P, nb)                                                          \
    do { WRQ(sq0, nb, 0, P##0, P##1);     WRQ(sq1, nb, 8192, P##2, P##3);     \
         WRQ(sq2, nb, 16384, P##4, P##5); WRQ(sq3, nb, 24576, P##6, P##7); } while (0)

    // read addressing: row pitch 64B; phys slot = lg ^ ((l15>>1)&3)
    int qi = w & 3, qr = qi >> 1, qc = qi & 1;
    int Aoff = (w < 4) ? 0 : 8192;
    int Boff = (w < 4) ? 16384 : 24576;
    int slot = (lg ^ ((l15 >> 1) & 3)) * 16;
    int Abase = Aoff + (qr * 64 + l15) * 64 + slot;   // +i*1024
    int Bbase = Boff + (qc * 64 + l15) * 64 + slot;   // +j*1024

    f32x4 c00 = {0.f,0.f,0.f,0.f}, c01 = c00, c02 = c00, c03 = c00;
    f32x4 c10 = c00, c11 = c00, c12 = c00, c13 = c00;
    f32x4 c20 = c00, c21 = c00, c22 = c00, c23 = c00;
    f32x4 c30 = c00, c31 = c00, c32 = c00, c33 = c00;

#define MM(i, j, fa, fb) c##i##j = __builtin_amdgcn_mfma_f32_16x16x32_bf16(fa, fb, c##i##j, 0, 0, 0)
#define COMPUTE(cb)                                                           \
    do {                                                                      \
        const char* bp = smem + (cb);                                         \
        short8 fa0 = *(const short8*)(bp + Abase + 0);                        \
        short8 fa1 = *(const short8*)(bp + Abase + 1024);                     \
        short8 fa2 = *(const short8*)(bp + Abase + 2048);                     \
        short8 fa3 = *(const short8*)(bp + Abase + 3072);                     \
        short8 g0 = *(const short8*)(bp + Bbase + 0);                         \
        short8 g1 = *(const short8*)(bp + Bbase + 1024);                      \
        short8 g2 = *(const short8*)(bp + Bbase + 2048);                      \
        short8 g3 = *(const short8*)(bp + Bbase + 3072);                      \
        __builtin_amdgcn_s_setprio(1);                                        \
        MM(0,0,fa0,g0); MM(1,0,fa1,g0); MM(2,0,fa2,g0); MM(3,0,fa3,g0);       \
        MM(0,1,fa0,g1); MM(1,1,fa1,g1); MM(2,1,fa2,g1); MM(3,1,fa3,g1);       \
        MM(0,2,fa0,g2); MM(1,2,fa1,g2); MM(2,2,fa2,g2); MM(3,2,fa3,g2);       \
        MM(0,3,fa0,g3); MM(1,3,fa1,g3); MM(2,3,fa2,g3); MM(3,3,fa3,g3);       \
        __builtin_amdgcn_s_setprio(0);                                        \
    } while (0)

    // prologue: tile0 -> buf0 (one stall, once); tiles 1,2 into O,E in flight
    LDSET(E, 0);
    WRSET(E, 0);
    LDSET(O, (size_t)BK);
    LDSET(E, (size_t)(2 * BK));
    __syncthreads();

    // invariant at iter t: buf t%2 = tile t (LDS); set[(t+1)%2] = tile t+1
    // (regs, loaded at iter t-2 -> rested ~2 iterations -> no vmcnt stall).
#pragma unroll 2
    for (int t = 0; t < 24; ++t) {
        int cb = (t & 1) * 32768;
        int nb = cb ^ 32768;
        COMPUTE(cb);
        if (t & 1) {                       // t odd: t+1 even -> set E
            if (t < 23) WRSET(E, nb);
            if (t < 21) LDSET(E, (size_t)(t + 3) * BK);
        } else {                           // t even: t+1 odd -> set O
            if (t < 23) WRSET(O, nb);
            if (t < 21) LDSET(O, (size_t)(t + 3) * BK);
        }
        __syncthreads();
    }
#undef COMPUTE
#undef MM
#undef WRSET
#undef WRQ
#undef LDSET

    // finalize norms: quad-reduce (lanes ln=0..3 share a row)
    sq0 += __shfl_xor(sq0, 1); sq0 += __shfl_xor(sq0, 2);
    sq1 += __shfl_xor(sq1, 1); sq1 += __shfl_xor(sq1, 2);
    sq2 += __shfl_xor(sq2, 1); sq2 += __shfl_xor(sq2, 2);
    sq3 += __shfl_xor(sq3, 1); sq3 += __shfl_xor(sq3, 2);
    if (ln == 0) {
        norms[srow] = sq0;
        norms[128 + srow] = sq1;
        norms[256 + srow] = sq2;
        norms[384 + srow] = sq3;
    }
    __syncthreads();

    // scale raw dots -> cosines: c[i][j][r] *= rsqrt(nA[p]) * rsqrt(nB[t])
    {
        const float* nA = norms + ((w < 4) ? 0 : 128);
        const float* nB = norms + ((w < 4) ? 256 : 384);
        float ivB0 = rsqrtf(nB[qc * 64 + 0 * 16 + l15]);
        float ivB1 = rsqrtf(nB[qc * 64 + 1 * 16 + l15]);
        float ivB2 = rsqrtf(nB[qc * 64 + 2 * 16 + l15]);
        float ivB3 = rsqrtf(nB[qc * 64 + 3 * 16 + l15]);
#define SCJ(ii, jj) { c##ii##jj[0] *= s0 * ivB##jj; c##ii##jj[1] *= s1 * ivB##jj; \
                      c##ii##jj[2] *= s2 * ivB##jj; c##ii##jj[3] *= s3 * ivB##jj; }
#define SCA(ii) { float s0 = rsqrtf(nA[qr * 64 + ii * 16 + lg * 4 + 0]);      \
                  float s1 = rsqrtf(nA[qr * 64 + ii * 16 + lg * 4 + 1]);      \
                  float s2 = rsqrtf(nA[qr * 64 + ii * 16 + lg * 4 + 2]);      \
                  float s3 = rsqrtf(nA[qr * 64 + ii * 16 + lg * 4 + 3]);      \
                  SCJ(ii,0) SCJ(ii,1) SCJ(ii,2) SCJ(ii,3) }
        SCA(0) SCA(1) SCA(2) SCA(3)
#undef SCA
#undef SCJ
    }
    __syncthreads();

    // epilogue (R7/R12-verified): H-wave wp + T-wave wp, swizzled quad exchange.
    float* bwv = (float*)(smem + 16384);          // [128][2]
    int*   bwt = (int*)(smem + 17408);            // [128][2]
    int wp = w & 3;
    char* xrow = smem + (wp * 64 + l) * 64;       // 16KB exchange region
    int qsw = (l >> 1) & 3;

#define XW(q, v) *(f32x4*)(xrow + (((q) ^ qsw) * 16)) = (v)
#define XR(q)    *(const f32x4*)(xrow + (((q) ^ qsw) * 16))

#define ASTEP(ii, jj, rr, TQ)                                                 \
        { float h = c##ii##jj[rr]; float tv = (TQ)[rr];                       \
          bool ok = (h > THRESH) && (tv > THRESH);                            \
          float sc = ok ? 0.5f * (h + tv) : -INFINITY;                        \
          if (sc > bv) { bv = sc; bt = qc * 64 + jj * 16 + l15; } }

#define AMX(ii, rr)                                                           \
    {   float bv = -INFINITY; int bt = 0x7fffffff;                            \
        ASTEP(ii, 0, rr, t0) ASTEP(ii, 1, rr, t1)                             \
        ASTEP(ii, 2, rr, t2) ASTEP(ii, 3, rr, t3)                             \
        for (int m = 1; m < 16; m <<= 1) {                                    \
            float v2 = __shfl_xor(bv, m); int q2 = __shfl_xor(bt, m);         \
            if (v2 > bv || (v2 == bv && q2 < bt)) { bv = v2; bt = q2; }       \
        }                                                                     \
        if (l15 == 0) { int p = qr * 64 + ii * 16 + lg * 4 + rr;              \
            bwv[p * 2 + qc] = bv; bwt[p * 2 + qc] = bt; }                     \
    }

#define EPI(ii)                                                               \
    if (w >= 4) { XW(0, c##ii##0); XW(1, c##ii##1);                           \
                  XW(2, c##ii##2); XW(3, c##ii##3); }                         \
    __syncthreads();                                                          \
    if (w < 4) {                                                              \
        f32x4 t0 = XR(0), t1 = XR(1), t2 = XR(2), t3 = XR(3);                 \
        AMX(ii, 0) AMX(ii, 1) AMX(ii, 2) AMX(ii, 3)                           \
    }                                                                         \
    __syncthreads();

    EPI(0)
    EPI(1)
    EPI(2)
    EPI(3)
#undef EPI
#undef AMX
#undef ASTEP
#undef XW
#undef XR

    if (tid < 128) {
        float v = bwv[tid * 2 + 0]; int t1 = bwt[tid * 2 + 0];
        float v2 = bwv[tid * 2 + 1]; int t2 = bwt[tid * 2 + 1];
        if (v2 > v || (v2 == v && t2 < t1)) { v = v2; t1 = t2; }
        int grow = b * PP + pblk * 128 + tid;
        cand_v[(size_t)grow * 4 + tblk] = v;
        cand_t[(size_t)grow * 4 + tblk] = (v > -INFINITY) ? (tblk * 128 + t1) : 0x7fffffff;
    }
}

// ---------------- stage 3: fused merge + per-row NLL -------------------------
__global__ void nll_kernel(const float* __restrict__ preds,
                           const float* __restrict__ cand_v,
                           const int* __restrict__ cand_t,
                           const float* __restrict__ trip,
                           float* __restrict__ partials) {
    int w = threadIdx.x >> 6, l = threadIdx.x & 63;
    int row = blockIdx.x * 4 + w;
    const float* x = preds + (size_t)row * CC;

    float v = (l < 4) ? cand_v[(size_t)row * 4 + l] : -INFINITY;
    int  tt = (l < 4) ? cand_t[(size_t)row * 4 + l] : 0x7fffffff;
#pragma unroll
    for (int m = 1; m < 4; m <<= 1) {
        float v2 = __shfl_xor(v, m); int t2 = __shfl_xor(tt, m);
        if (v2 > v || (v2 == v && t2 < tt)) { v = v2; tt = t2; }
    }
    int bb = row >> 9;
    int tg = 0;
    if (l == 0 && v > -INFINITY)
        tg = (int)trip[((size_t)bb * TT + tt) * (2 * DD + 1) + DD];
    tg = __shfl(tg, 0);

    float a = x[l];
    float b2 = (l + 64 < CC) ? x[l + 64] : -INFINITY;
    float mx = fmaxf(a, b2);
    for (int m = 32; m; m >>= 1) mx = fmaxf(mx, __shfl_xor(mx, m));
    float e = __expf(a - mx) + ((l + 64 < CC) ? __expf(b2 - mx) : 0.0f);
    for (int m = 32; m; m >>= 1) e += __shfl_xor(e, m);

    __shared__ float part[4];
    if (l == 0) part[w] = mx + logf(e) - x[tg];
    __syncthreads();
    if (threadIdx.x == 0)
        partials[blockIdx.x] = part[0] + part[1] + part[2] + part[3];
}

// ---------------- stage 4: final mean ----------------------------------------
__global__ void final_reduce_kernel(const float* __restrict__ partials, int n,
                                    float* __restrict__ out) {
    float s = 0.f;
    for (int i = threadIdx.x; i < n; i += 256) s += partials[i];
    for (int m = 32; m; m >>= 1) s += __shfl_xor(s, m);
    __shared__ float ps[4];
    if ((threadIdx.x & 63) == 0) ps[threadIdx.x >> 6] = s;
    __syncthreads();
    if (threadIdx.x == 0)
        out[0] = (ps[0] + ps[1] + ps[2] + ps[3]) / (float)(BB * PP);
}

extern "C" void kernel_launch(void* const* d_in, const int* in_sizes, int n_in,
                              void* d_out, int out_size, void* d_ws, size_t ws_size,
                              hipStream_t stream) {
    const float* pairs = (const float*)d_in[0];  // [B,P,1536]
    const float* preds = (const float*)d_in[1];  // [B,P,97]
    const float* trip  = (const float*)d_in[2];  // [B,T,1537]
    float* out = (float*)d_out;

    char* p = (char*)d_ws;
    float* cand_v = (float*)p;       p += (size_t)BB * PP * 4 * sizeof(float);  // 256KB
    int* cand_t = (int*)p;           p += (size_t)BB * PP * 4 * sizeof(int);    // 256KB
    float* partials = (float*)p;                                                // 16KB

    match_kernel<<<BB * 16, 512, 0, stream>>>(pairs, trip, cand_v, cand_t);
    nll_kernel<<<BB * PP / 4, 256, 0, stream>>>(preds, cand_v, cand_t, trip, partials);
    final_reduce_kernel<<<1, 256, 0, stream>>>(partials, BB * PP / 4, out);
}